// Round 1
// baseline (18864.113 us; speedup 1.0000x reference)
//
#include <hip/hip_runtime.h>
#include <math.h>

#define MC      50000
#define MPATHS  100000   // 2*MC antithetic
#define NSTEPS  180
#define WIDTH   64
#define NOPTS   32

// One thread = one path. Persistent over all 180 steps; S,V in registers.
// Weights are wave-uniform -> expect scalar (s_load) weight fetches.
// Payoffs accumulated on the fly at maturity steps (no path storage).
__global__ __launch_bounds__(64, 4)
void sde_kernel(const float* __restrict__ x,
                const float* __restrict__ z,
                const float* __restrict__ z1,
                const float* __restrict__ W1, const float* __restrict__ b1,
                const float* __restrict__ W2, const float* __restrict__ b2,
                const float* __restrict__ Wo, const float* __restrict__ bo,
                float* __restrict__ acc)
{
    __shared__ int   ls_mat[NOPTS];
    __shared__ float ls_k[NOPTS];
    const int tid = threadIdx.x;
    if (tid < NOPTS) {
        ls_mat[tid] = (int)x[tid * 2];
        ls_k[tid]   = x[tid * 2 + 1];
    }
    __syncthreads();

    const int p = blockIdx.x * 64 + tid;
    const float w = (p < MPATHS) ? 1.0f : 0.0f;   // ghost paths contribute 0
    int pc = (p < MPATHS) ? p : (MPATHS - 1);
    float sgn = 1.0f;
    int row = pc;
    if (pc >= MC) { sgn = -1.0f; row = pc - MC; }
    const float* __restrict__ zrow  = z  + (size_t)row * NSTEPS;
    const float* __restrict__ z1row = z1 + (size_t)row * NSTEPS;

    const float hh  = 1.0f / 360.0f;
    const float sqh = sqrtf(hh);
    const float s75 = 0.86602540378443864676f;  // fp32(sqrt(0.75))
    const float rate = 0.025f;

    float S = 100.0f, V = 0.04f;

    for (int i = 0; i < NSTEPS; ++i) {
        const float zc  = sgn * zrow[i];
        const float z1v = sgn * (-0.5f * zrow[i] + s75 * z1row[i]);
        const float dW  = sqh * zc;
        const float dW1 = sqh * z1v;
        const float t   = (float)i * hh;

        float dS = 0.0f, dV = 0.0f;

        #pragma unroll 1   // keep nets rolled: I$ + SGPR pressure
        for (int n = 0; n < 4; ++n) {
            // ---- layer 1: 4 -> 64 ----
            const float* __restrict__ w1  = W1 + n * WIDTH * 4;
            const float* __restrict__ bb1 = b1 + n * WIDTH;
            float h1[WIDTH];
            #pragma unroll
            for (int u = 0; u < WIDTH; ++u) {
                float a = bb1[u];
                a = fmaf(w1[u * 4 + 0], t,    a);
                a = fmaf(w1[u * 4 + 1], S,    a);
                a = fmaf(w1[u * 4 + 2], V,    a);
                a = fmaf(w1[u * 4 + 3], rate, a);
                h1[u] = fmaxf(a, 0.0f);
            }
            // ---- layer 2 (64x64) fused with output layer ----
            const float* __restrict__ w2  = W2 + n * WIDTH * WIDTH;
            const float* __restrict__ bb2 = b2 + n * WIDTH;
            const float* __restrict__ wo  = Wo + n * WIDTH;
            float out = bo[n];
            #pragma unroll 1   // rolled: 16 iters x (256 fma) fits I$
            for (int j = 0; j < WIDTH; j += 4) {
                float a0 = bb2[j + 0];
                float a1 = bb2[j + 1];
                float a2 = bb2[j + 2];
                float a3 = bb2[j + 3];
                #pragma unroll
                for (int k = 0; k < WIDTH; ++k) {
                    const float hv = h1[k];
                    a0 = fmaf(w2[(j + 0) * WIDTH + k], hv, a0);
                    a1 = fmaf(w2[(j + 1) * WIDTH + k], hv, a1);
                    a2 = fmaf(w2[(j + 2) * WIDTH + k], hv, a2);
                    a3 = fmaf(w2[(j + 3) * WIDTH + k], hv, a3);
                }
                out = fmaf(wo[j + 0], fmaxf(a0, 0.0f), out);
                out = fmaf(wo[j + 1], fmaxf(a1, 0.0f), out);
                out = fmaf(wo[j + 2], fmaxf(a2, 0.0f), out);
                out = fmaf(wo[j + 3], fmaxf(a3, 0.0f), out);
            }
            // route net outputs: 0=driftS,1=diffS,2=driftV,3=diffV (n uniform)
            const float ms = (n == 0) ? hh : ((n == 1) ? dW  : 0.0f);
            const float mv = (n == 2) ? hh : ((n == 3) ? dW1 : 0.0f);
            dS = fmaf(out, ms, dS);
            dV = fmaf(out, mv, dV);
        }

        S = fmaxf(S + dS, 0.0f);
        V = fmaxf(V + dV, 0.0f);

        // on-the-fly payoff accumulation for options maturing at day i+1
        const int day = i + 1;
        #pragma unroll 1
        for (int q = 0; q < NOPTS; ++q) {
            if (ls_mat[q] == day) {
                float pay = w * fmaxf(S - ls_k[q], 0.0f);
                #pragma unroll
                for (int off = 32; off > 0; off >>= 1)
                    pay += __shfl_down(pay, off, 64);
                if (tid == 0) atomicAdd(&acc[q], pay);
            }
        }
    }
}

__global__ void price_kernel(const float* __restrict__ x,
                             const float* __restrict__ acc,
                             float* __restrict__ out)
{
    const int q = threadIdx.x;
    if (q < NOPTS) {
        const float mat = x[q * 2];
        const float disc = expf((-0.025f * mat) / 360.0f);
        out[q] = acc[q] * (1.0f / (float)MPATHS) * disc;
    }
}

extern "C" void kernel_launch(void* const* d_in, const int* in_sizes, int n_in,
                              void* d_out, int out_size, void* d_ws, size_t ws_size,
                              hipStream_t stream)
{
    const float* x  = (const float*)d_in[0];
    const float* z  = (const float*)d_in[1];
    const float* z1 = (const float*)d_in[2];
    const float* W1 = (const float*)d_in[3];
    const float* b1 = (const float*)d_in[4];
    const float* W2 = (const float*)d_in[5];
    const float* b2 = (const float*)d_in[6];
    const float* Wo = (const float*)d_in[7];
    const float* bo = (const float*)d_in[8];

    float* acc = (float*)d_ws;                       // 32 floats of scratch
    hipMemsetAsync(acc, 0, NOPTS * sizeof(float), stream);

    const int grid = (MPATHS + 63) / 64;             // 1563 blocks x 1 wave
    sde_kernel<<<grid, 64, 0, stream>>>(x, z, z1, W1, b1, W2, b2, Wo, bo, acc);
    price_kernel<<<1, 64, 0, stream>>>(x, acc, (float*)d_out);
}

// Round 4
// 12808.672 us; speedup vs baseline: 1.4728x; 1.4728x over previous
//
#include <hip/hip_runtime.h>
#include <math.h>

#define MC      50000
#define MPATHS  100000   // 2*MC antithetic
#define NSTEPS  180
#define NOPTS   32

typedef _Float16 half2v __attribute__((ext_vector_type(2)));

// v_dot2_f32_f16: c += a.x*b.x + a.y*b.y  (per-lane, layout-free, arg-symmetric)
static __device__ __forceinline__ float fdot2(unsigned w, unsigned h, float c) {
#if __has_builtin(__builtin_amdgcn_fdot2)
    return __builtin_amdgcn_fdot2(__builtin_bit_cast(half2v, w),
                                  __builtin_bit_cast(half2v, h), c, false);
#else
    half2v a = __builtin_bit_cast(half2v, w);
    half2v b = __builtin_bit_cast(half2v, h);
    return fmaf((float)a.x, (float)b.x, fmaf((float)a.y, (float)b.y, c));
#endif
}

static __device__ __forceinline__ unsigned pkh2(float a, float b) {
    half2v h; h.x = (_Float16)a; h.y = (_Float16)b;   // RNE casts, .x = low half
    return __builtin_bit_cast(unsigned, h);
}

// pre-kernel: pack W2 (4x64x64 f32) into f16x2 pairs (contiguous k-pairs)
__global__ void pack_w2(const float* __restrict__ W2, unsigned* __restrict__ wp2) {
    int i = blockIdx.x * 256 + threadIdx.x;           // pair index, 8192 total
    if (i < 4 * 64 * 32)
        wp2[i] = pkh2(W2[2 * i], W2[2 * i + 1]);
}

// One thread = one path, persistent over 180 steps. Layer1 + epilogue fp32;
// layer2 (64x64, 93% of FLOPs) via v_dot2_f32_f16 with f16 h1 kept packed in
// 32 VGPRs (all indices compile-time const). Weights wave-uniform -> s_load.
__global__ __launch_bounds__(64)
void sde_dot2(const float* __restrict__ x,
              const float* __restrict__ z,
              const float* __restrict__ z1,
              const float* __restrict__ W1, const float* __restrict__ b1,
              const float* __restrict__ b2, const float* __restrict__ Wo,
              const float* __restrict__ bo,
              const unsigned* __restrict__ wp2,
              float* __restrict__ acc)
{
    __shared__ float ls_k[NOPTS];
    __shared__ int   maskTab[NSTEPS + 4];

    const int tid = threadIdx.x;
    for (int jj = tid; jj < NSTEPS + 4; jj += 64) maskTab[jj] = 0;
    if (tid < NOPTS) ls_k[tid] = x[2 * tid + 1];
    __syncthreads();
    if (tid < NOPTS) atomicOr(&maskTab[(int)x[2 * tid]], 1 << tid);
    __syncthreads();

    const int p_ = blockIdx.x * 64 + tid;
    const float wgt = (p_ < MPATHS) ? 1.0f : 0.0f;    // ghost lanes weightless
    int pc = (p_ < MPATHS) ? p_ : (MPATHS - 1);
    float sgn = 1.0f; int row = pc;
    if (pc >= MC) { sgn = -1.0f; row -= MC; }
    const float* __restrict__ zrow  = z  + (size_t)row * NSTEPS;
    const float* __restrict__ z1row = z1 + (size_t)row * NSTEPS;

    const float hh   = 1.0f / 360.0f;
    const float sqh  = sqrtf(hh);
    const float s75  = 0.86602540378443864676f;
    const float rate = 0.025f;

    float S = 100.0f, V = 0.04f;

    #pragma unroll 1
    for (int i = 0; i < NSTEPS; ++i) {
        const float zcr = zrow[i];
        const float z1r = z1row[i];
        const float dW  = sqh * (sgn * zcr);
        const float dW1 = sqh * (sgn * (-0.5f * zcr + s75 * z1r));
        const float t   = (float)i * hh;

        float dS = 0.0f, dV = 0.0f;

        #pragma unroll 1   // rolled: ~2.7K instr body fits I$
        for (int net = 0; net < 4; ++net) {
            const float*    __restrict__ w1n  = W1  + net * 256;
            const float*    __restrict__ b1n  = b1  + net * 64;
            const float*    __restrict__ b2n  = b2  + net * 64;
            const float*    __restrict__ won  = Wo  + net * 64;
            const unsigned* __restrict__ wp2n = wp2 + net * 2048;

            // ---- layer 1 (fp32, inputs unquantized) + pack h1 to f16x2 ----
            unsigned h1p[32];
            #pragma unroll
            for (int u = 0; u < 64; u += 2) {
                float a0 = b1n[u];
                float a1 = b1n[u + 1];
                a0 = fmaf(w1n[4 * u + 0], t,    a0);
                a0 = fmaf(w1n[4 * u + 1], S,    a0);
                a0 = fmaf(w1n[4 * u + 2], V,    a0);
                a0 = fmaf(w1n[4 * u + 3], rate, a0);
                a1 = fmaf(w1n[4 * u + 4], t,    a1);
                a1 = fmaf(w1n[4 * u + 5], S,    a1);
                a1 = fmaf(w1n[4 * u + 6], V,    a1);
                a1 = fmaf(w1n[4 * u + 7], rate, a1);
                h1p[u >> 1] = pkh2(fmaxf(a0, 0.0f), fmaxf(a1, 0.0f));
            }

            // ---- layer 2 (dot2) + fused output layer ----
            float outn = bo[net];
            #pragma unroll 1   // 16 iters x (128 dot2 + epilogue)
            for (int j = 0; j < 64; j += 4) {
                const unsigned* __restrict__ wr = wp2n + j * 32;
                float a0 = b2n[j + 0];
                float a1 = b2n[j + 1];
                float a2 = b2n[j + 2];
                float a3 = b2n[j + 3];
                #pragma unroll
                for (int k2 = 0; k2 < 32; ++k2) {
                    const unsigned hv = h1p[k2];
                    a0 = fdot2(wr[k2],      hv, a0);
                    a1 = fdot2(wr[32 + k2], hv, a1);
                    a2 = fdot2(wr[64 + k2], hv, a2);
                    a3 = fdot2(wr[96 + k2], hv, a3);
                }
                outn = fmaf(won[j + 0], fmaxf(a0, 0.0f), outn);
                outn = fmaf(won[j + 1], fmaxf(a1, 0.0f), outn);
                outn = fmaf(won[j + 2], fmaxf(a2, 0.0f), outn);
                outn = fmaf(won[j + 3], fmaxf(a3, 0.0f), outn);
            }

            // route: 0=driftS, 1=diffS, 2=driftV, 3=diffV
            const float ms = (net == 0) ? hh : (net == 1) ? dW  : 0.0f;
            const float mv = (net == 2) ? hh : (net == 3) ? dW1 : 0.0f;
            dS = fmaf(outn, ms, dS);
            dV = fmaf(outn, mv, dV);
        }

        S = fmaxf(S + dS, 0.0f);
        V = fmaxf(V + dV, 0.0f);

        // ---- on-the-fly payoff at maturities ----
        int mm = maskTab[i + 1];
        while (mm) {
            int qq = __ffs(mm) - 1; mm &= mm - 1;
            float pay = wgt * fmaxf(S - ls_k[qq], 0.0f);
            #pragma unroll
            for (int off = 32; off > 0; off >>= 1)
                pay += __shfl_down(pay, off, 64);
            if (tid == 0) atomicAdd(&acc[qq], pay);
        }
    }
}

__global__ void price_kernel(const float* __restrict__ x,
                             const float* __restrict__ acc,
                             float* __restrict__ out)
{
    const int q = threadIdx.x;
    if (q < NOPTS) {
        const float mat = x[q * 2];
        const float disc = expf((-0.025f * mat) / 360.0f);
        out[q] = acc[q] * (1.0f / (float)MPATHS) * disc;
    }
}

extern "C" void kernel_launch(void* const* d_in, const int* in_sizes, int n_in,
                              void* d_out, int out_size, void* d_ws, size_t ws_size,
                              hipStream_t stream)
{
    const float* x  = (const float*)d_in[0];
    const float* z  = (const float*)d_in[1];
    const float* z1 = (const float*)d_in[2];
    const float* W1 = (const float*)d_in[3];
    const float* b1 = (const float*)d_in[4];
    const float* W2 = (const float*)d_in[5];
    const float* b2 = (const float*)d_in[6];
    const float* Wo = (const float*)d_in[7];
    const float* bo = (const float*)d_in[8];

    float*    acc = (float*)d_ws;                      // [0,128): accumulators
    unsigned* wp2 = (unsigned*)((char*)d_ws + 256);    // 32KB packed W2

    hipMemsetAsync(acc, 0, NOPTS * sizeof(float), stream);
    pack_w2<<<(8192 + 255) / 256, 256, 0, stream>>>(W2, wp2);

    const int grid = (MPATHS + 63) / 64;               // 1563 blocks x 1 wave
    sde_dot2<<<grid, 64, 0, stream>>>(x, z, z1, W1, b1, b2, Wo, bo, wp2, acc);
    price_kernel<<<1, 64, 0, stream>>>(x, acc, (float*)d_out);
}

// Round 6
// 9086.203 us; speedup vs baseline: 2.0761x; 1.4097x over previous
//
#include <hip/hip_runtime.h>
#include <math.h>

#define MC      50000
#define MPATHS  100000   // 2*MC antithetic
#define NSTEPS  180
#define NOPTS   32

typedef _Float16 half2v __attribute__((ext_vector_type(2)));
typedef unsigned u32x32 __attribute__((ext_vector_type(32)));

// v_dot2_f32_f16: c += a.x*b.x + a.y*b.y (per-lane, layout-free)
static __device__ __forceinline__ float fdot2(unsigned w, unsigned h, float c) {
    return __builtin_amdgcn_fdot2(__builtin_bit_cast(half2v, w),
                                  __builtin_bit_cast(half2v, h), c, false);
}
// RNE f16 pair pack (pre-kernel only)
static __device__ __forceinline__ unsigned pkh2(float a, float b) {
    half2v h; h.x = (_Float16)a; h.y = (_Float16)b;   // .x = low half
    return __builtin_bit_cast(unsigned, h);
}
// fast RTZ pack (main loop, per-step inputs); builtin returns __fp16x2 -> bit_cast
static __device__ __forceinline__ unsigned pkrtz(float a, float b) {
    auto h = __builtin_amdgcn_cvt_pkrtz(a, b);
    return __builtin_bit_cast(unsigned, h);
}

// pack W1 (4x64x4) and W2 (4x64x64) f32 -> f16x2 pairs (natural pair order)
__global__ void pack_w(const float* __restrict__ W1, const float* __restrict__ W2,
                       unsigned* __restrict__ wp1, unsigned* __restrict__ wp2) {
    int i = blockIdx.x * 256 + threadIdx.x;
    if (i < 512)              wp1[i] = pkh2(W1[2 * i], W1[2 * i + 1]);
    else if (i < 512 + 8192) { int k = i - 512; wp2[k] = pkh2(W2[2 * k], W2[2 * k + 1]); }
}

// One thread = one path, persistent over 180 steps. Both layers via dot2.
// h1 kept packed f16x2 in an ext_vector (SSA value -> guaranteed VGPRs).
__global__ __launch_bounds__(64, 2)
void sde_dot2(const float* __restrict__ x,
              const float* __restrict__ z,
              const float* __restrict__ z1,
              const float* __restrict__ b1, const float* __restrict__ b2,
              const float* __restrict__ Wo, const float* __restrict__ bo,
              const unsigned* __restrict__ wp1,
              const unsigned* __restrict__ wp2,
              float* __restrict__ acc)
{
    __shared__ float ls_k[NOPTS];
    __shared__ int   maskTab[NSTEPS + 4];

    const int tid = threadIdx.x;
    for (int jj = tid; jj < NSTEPS + 4; jj += 64) maskTab[jj] = 0;
    if (tid < NOPTS) ls_k[tid] = x[2 * tid + 1];
    __syncthreads();
    if (tid < NOPTS) atomicOr(&maskTab[(int)x[2 * tid]], 1 << tid);
    __syncthreads();

    const int p_ = blockIdx.x * 64 + tid;
    const float wgt = (p_ < MPATHS) ? 1.0f : 0.0f;    // ghost lanes weightless
    int pc = (p_ < MPATHS) ? p_ : (MPATHS - 1);
    float sgn = 1.0f; int row = pc;
    if (pc >= MC) { sgn = -1.0f; row -= MC; }
    const float* __restrict__ zrow  = z  + (size_t)row * NSTEPS;
    const float* __restrict__ z1row = z1 + (size_t)row * NSTEPS;

    const float hh   = 1.0f / 360.0f;
    const float sqh  = sqrtf(hh);
    const float s75  = 0.86602540378443864676f;
    const float rate = 0.025f;

    float S = 100.0f, V = 0.04f;

    #pragma unroll 1
    for (int i = 0; i < NSTEPS; ++i) {
        const float zcr = zrow[i];
        const float z1r = z1row[i];
        const float dW  = sqh * (sgn * zcr);
        const float dW1 = sqh * (sgn * (-0.5f * zcr + s75 * z1r));
        const float t   = (float)i * hh;

        const unsigned in01 = pkrtz(t, S);     // (t, S)
        const unsigned in23 = pkrtz(V, rate);  // (V, rate)

        float dS = 0.0f, dV = 0.0f;

        #pragma unroll 1   // net loop rolled: body fits I$
        for (int net = 0; net < 4; ++net) {
            const float*    __restrict__ b1n  = b1  + net * 64;
            const float*    __restrict__ b2n  = b2  + net * 64;
            const float*    __restrict__ won  = Wo  + net * 64;
            const unsigned* __restrict__ wp1n = wp1 + net * 128;
            const unsigned* __restrict__ wp2n = wp2 + net * 2048;

            // ---- layer 1 (dot2) -> packed f16 h1 in an SSA vector ----
            u32x32 h1p;
            #pragma unroll
            for (int u = 0; u < 64; u += 2) {
                float a0 = fdot2(wp1n[2 * u + 0], in01, b1n[u]);
                a0 = fdot2(wp1n[2 * u + 1], in23, a0);
                float a1 = fdot2(wp1n[2 * u + 2], in01, b1n[u + 1]);
                a1 = fdot2(wp1n[2 * u + 3], in23, a1);
                h1p[u >> 1] = pkrtz(fmaxf(a0, 0.0f), fmaxf(a1, 0.0f));
            }

            // ---- layer 2 (dot2, fully unrolled) + fused output layer ----
            float outn = bo[net];
            #pragma unroll
            for (int j = 0; j < 64; j += 4) {
                const unsigned* __restrict__ wr = wp2n + j * 32;
                float a0 = b2n[j + 0];
                float a1 = b2n[j + 1];
                float a2 = b2n[j + 2];
                float a3 = b2n[j + 3];
                #pragma unroll
                for (int k2 = 0; k2 < 32; ++k2) {
                    const unsigned hv = h1p[k2];
                    a0 = fdot2(wr[k2],      hv, a0);
                    a1 = fdot2(wr[32 + k2], hv, a1);
                    a2 = fdot2(wr[64 + k2], hv, a2);
                    a3 = fdot2(wr[96 + k2], hv, a3);
                }
                outn = fmaf(won[j + 0], fmaxf(a0, 0.0f), outn);
                outn = fmaf(won[j + 1], fmaxf(a1, 0.0f), outn);
                outn = fmaf(won[j + 2], fmaxf(a2, 0.0f), outn);
                outn = fmaf(won[j + 3], fmaxf(a3, 0.0f), outn);
            }

            // route: 0=driftS, 1=diffS, 2=driftV, 3=diffV
            const float ms = (net == 0) ? hh : (net == 1) ? dW  : 0.0f;
            const float mv = (net == 2) ? hh : (net == 3) ? dW1 : 0.0f;
            dS = fmaf(outn, ms, dS);
            dV = fmaf(outn, mv, dV);
        }

        S = fmaxf(S + dS, 0.0f);
        V = fmaxf(V + dV, 0.0f);

        // ---- on-the-fly payoff at maturities ----
        int mm = maskTab[i + 1];
        while (mm) {
            int qq = __ffs(mm) - 1; mm &= mm - 1;
            float pay = wgt * fmaxf(S - ls_k[qq], 0.0f);
            #pragma unroll
            for (int off = 32; off > 0; off >>= 1)
                pay += __shfl_down(pay, off, 64);
            if (tid == 0) atomicAdd(&acc[qq], pay);
        }
    }
}

__global__ void price_kernel(const float* __restrict__ x,
                             const float* __restrict__ acc,
                             float* __restrict__ out)
{
    const int q = threadIdx.x;
    if (q < NOPTS) {
        const float mat = x[q * 2];
        const float disc = expf((-0.025f * mat) / 360.0f);
        out[q] = acc[q] * (1.0f / (float)MPATHS) * disc;
    }
}

extern "C" void kernel_launch(void* const* d_in, const int* in_sizes, int n_in,
                              void* d_out, int out_size, void* d_ws, size_t ws_size,
                              hipStream_t stream)
{
    const float* x  = (const float*)d_in[0];
    const float* z  = (const float*)d_in[1];
    const float* z1 = (const float*)d_in[2];
    const float* W1 = (const float*)d_in[3];
    const float* b1 = (const float*)d_in[4];
    const float* W2 = (const float*)d_in[5];
    const float* b2 = (const float*)d_in[6];
    const float* Wo = (const float*)d_in[7];
    const float* bo = (const float*)d_in[8];

    float*    acc = (float*)d_ws;                      // 128B accumulators
    unsigned* wp1 = (unsigned*)((char*)d_ws + 256);    // 2KB  packed W1
    unsigned* wp2 = wp1 + 512;                         // 32KB packed W2

    (void)hipMemsetAsync(acc, 0, NOPTS * sizeof(float), stream);
    pack_w<<<(512 + 8192 + 255) / 256, 256, 0, stream>>>(W1, W2, wp1, wp2);

    const int grid = (MPATHS + 63) / 64;               // 1563 blocks x 1 wave
    sde_dot2<<<grid, 64, 0, stream>>>(x, z, z1, b1, b2, Wo, bo, wp1, wp2, acc);
    price_kernel<<<1, 64, 0, stream>>>(x, acc, (float*)d_out);
}